// Round 1
// baseline (2961.281 us; speedup 1.0000x reference)
//
#include <hip/hip_runtime.h>
#include <math.h>

#define B_ 4
#define L_ 1024
#define DM 256
#define DIN 512
#define NST 16
#define DTR 16

__device__ __forceinline__ float softplusf(float x) {
    return (x > 20.f) ? x : log1pf(__expf(x));
}
__device__ __forceinline__ float siluf(float x) {
    return x / (1.f + __expf(-x));
}

// two-value block reduction (sum) over 256 threads = 4 waves
__device__ __forceinline__ void block_reduce2(float& a, float& q) {
    #pragma unroll
    for (int off = 32; off > 0; off >>= 1) {
        a += __shfl_down(a, off);
        q += __shfl_down(q, off);
    }
    __shared__ float sa[4], sq[4];
    int lane = threadIdx.x & 63, w = threadIdx.x >> 6;
    if (lane == 0) { sa[w] = a; sq[w] = q; }
    __syncthreads();
    a = sa[0] + sa[1] + sa[2] + sa[3];
    q = sq[0] + sq[1] + sq[2] + sq[3];
}

// ---- input projection: h0[b,l,d] = bias[d] + sum_c x[b,c,l] * W[d,c] ----
__global__ __launch_bounds__(256) void input_proj_kernel(
    const float* __restrict__ x, const float* __restrict__ W,
    const float* __restrict__ bias, float* __restrict__ h0)
{
    int idx = blockIdx.x * 256 + threadIdx.x;     // B*L*DM, d fastest
    int d = idx & (DM - 1);
    int bl = idx >> 8;
    int l = bl & (L_ - 1);
    int b = bl >> 10;
    const float* xb = x + (size_t)b * 3 * L_;
    float acc = bias[d];
    acc = fmaf(xb[0 * L_ + l], W[d * 3 + 0], acc);
    acc = fmaf(xb[1 * L_ + l], W[d * 3 + 1], acc);
    acc = fmaf(xb[2 * L_ + l], W[d * 3 + 2], acc);
    h0[idx] = acc;
}

// ---- layernorm over last dim (256), one block per (b,l) row ----
__global__ __launch_bounds__(256) void ln_kernel(
    const float* __restrict__ x, const float* __restrict__ w,
    const float* __restrict__ bb, float* __restrict__ o)
{
    int row = blockIdx.x;
    int t = threadIdx.x;
    float v = x[(size_t)row * DM + t];
    float a = v, q = v * v;
    block_reduce2(a, q);
    float mu = a * (1.f / DM);
    float var = q * (1.f / DM) - mu * mu;
    o[(size_t)row * DM + t] = (v - mu) * rsqrtf(var + 1e-5f) * w[t] + bb[t];
}

// ---- GEMM: C[M,N] (+)= A[M,K] @ W[N,K]^T ; 64x64 tile, 256 thr, 4x4/thr ----
__global__ __launch_bounds__(256) void gemm_tn(
    const float* __restrict__ A, const float* __restrict__ W,
    float* C, int M, int N, int K, int accumulate)
{
    __shared__ float As[16][68];
    __shared__ float Ws[16][68];
    const int tx = threadIdx.x & 15;
    const int ty = threadIdx.x >> 4;
    const int m0 = blockIdx.y * 64;
    const int n0 = blockIdx.x * 64;
    const int lr = threadIdx.x >> 2;         // 0..63
    const int lk = (threadIdx.x & 3) * 4;    // 0,4,8,12
    float acc[4][4] = {};
    for (int k0 = 0; k0 < K; k0 += 16) {
        float4 av = *(const float4*)(A + (size_t)(m0 + lr) * K + (k0 + lk));
        int wn = n0 + lr;
        float4 wv = make_float4(0.f, 0.f, 0.f, 0.f);
        if (wn < N) wv = *(const float4*)(W + (size_t)wn * K + (k0 + lk));
        As[lk + 0][lr] = av.x; As[lk + 1][lr] = av.y;
        As[lk + 2][lr] = av.z; As[lk + 3][lr] = av.w;
        Ws[lk + 0][lr] = wv.x; Ws[lk + 1][lr] = wv.y;
        Ws[lk + 2][lr] = wv.z; Ws[lk + 3][lr] = wv.w;
        __syncthreads();
        #pragma unroll
        for (int k = 0; k < 16; ++k) {
            float4 a4 = *(const float4*)&As[k][ty * 4];
            float4 w4 = *(const float4*)&Ws[k][tx * 4];
            float ar[4] = {a4.x, a4.y, a4.z, a4.w};
            float wr[4] = {w4.x, w4.y, w4.z, w4.w};
            #pragma unroll
            for (int i = 0; i < 4; ++i)
                #pragma unroll
                for (int j = 0; j < 4; ++j)
                    acc[i][j] = fmaf(ar[i], wr[j], acc[i][j]);
        }
        __syncthreads();
    }
    #pragma unroll
    for (int i = 0; i < 4; ++i) {
        int m = m0 + ty * 4 + i;
        int n = n0 + tx * 4;
        if (n + 3 < N) {
            float* cp = C + (size_t)m * N + n;
            float4 cv;
            if (accumulate) {
                cv = *(const float4*)cp;
                cv.x += acc[i][0]; cv.y += acc[i][1];
                cv.z += acc[i][2]; cv.w += acc[i][3];
            } else {
                cv = make_float4(acc[i][0], acc[i][1], acc[i][2], acc[i][3]);
            }
            *(float4*)cp = cv;
        }
    }
}

// ---- causal depthwise conv (k=4) + silu: xz[:, :, :512] -> xc ----
__global__ __launch_bounds__(256) void conv_silu_kernel(
    const float* __restrict__ xz, const float* __restrict__ cw,
    const float* __restrict__ cb, float* __restrict__ xc)
{
    int idx = blockIdx.x * 256 + threadIdx.x;   // B*L*DIN, d fastest
    int d = idx & (DIN - 1);
    int bl = idx >> 9;
    int l = bl & (L_ - 1);
    int b = bl >> 10;
    float acc = cb[d];
    #pragma unroll
    for (int k = 0; k < 4; ++k) {
        int ls = l - 3 + k;
        if (ls >= 0)
            acc = fmaf(xz[((size_t)(b * L_ + ls)) * (2 * DIN) + d], cw[d * 4 + k], acc);
    }
    xc[idx] = siluf(acc);
}

// ---- delta[b,l,d] = softplus(dbc[b,l,0:16] . dt_w[d,:] + dt_b[d]) ----
__global__ __launch_bounds__(256) void dt_kernel(
    const float* __restrict__ dbc, const float* __restrict__ dt_w,
    const float* __restrict__ dt_b, float* __restrict__ delta)
{
    int idx = blockIdx.x * 256 + threadIdx.x;   // B*L*DIN, d fastest
    int d = idx & (DIN - 1);
    int bl = idx >> 9;
    const float* dr = dbc + (size_t)bl * 48;
    const float* wr = dt_w + d * DTR;
    float acc = dt_b[d];
    #pragma unroll
    for (int r = 0; r < DTR; ++r)
        acc = fmaf(dr[r], wr[r], acc);
    delta[idx] = softplusf(acc);
}

// ---- selective scan, fused with D_skip and silu(z) gate ----
// grid (DIN/16, B), block 256 = 16 d-channels x 16 states; lane = dl*16 + n
// NOTE: `delta` and `y` may alias (y[b,l,d] overwrites delta[b,l,d] after the
// last read of it) -> intentionally NOT __restrict__.
__global__ __launch_bounds__(256) void scan_kernel(
    const float* delta, const float* __restrict__ dbc,
    const float* __restrict__ xc, const float* __restrict__ xz,
    const float* __restrict__ A_log, const float* __restrict__ Dskip,
    float* y)
{
    const int n = threadIdx.x & 15;
    const int dl = threadIdx.x >> 4;
    const int d = blockIdx.x * 16 + dl;
    const int b = blockIdx.y;
    const float A = -__expf(A_log[d * NST + n]);
    const float Dsk = Dskip[d];
    const float* dptr = delta + (size_t)b * L_ * DIN + d;
    const float* xcp  = xc    + (size_t)b * L_ * DIN + d;
    const float* zp   = xz    + (size_t)b * L_ * (2 * DIN) + DIN + d;
    const float* bcp  = dbc   + (size_t)b * L_ * 48;
    float* yp         = y     + (size_t)b * L_ * DIN + d;

    float h = 0.f;
    float dlt = dptr[0];
    float xcv = xcp[0];
    float Bv = bcp[DTR + n];
    float Cv = bcp[DTR + NST + n];
    for (int l = 0; l < L_; ++l) {
        int lp = (l < L_ - 1) ? l + 1 : l;           // prefetch next step
        float dlt_n = dptr[(size_t)lp * DIN];
        float xcv_n = xcp[(size_t)lp * DIN];
        float Bv_n  = bcp[(size_t)lp * 48 + DTR + n];
        float Cv_n  = bcp[(size_t)lp * 48 + DTR + NST + n];

        float dA = __expf(dlt * A);
        h = fmaf(dA, h, dlt * Bv * xcv);
        float p = h * Cv;
        p += __shfl_xor(p, 1);
        p += __shfl_xor(p, 2);
        p += __shfl_xor(p, 4);
        p += __shfl_xor(p, 8);
        if (n == 0) {
            float zv = zp[(size_t)l * (2 * DIN)];
            yp[(size_t)l * DIN] = (p + xcv * Dsk) * siluf(zv);
        }
        dlt = dlt_n; xcv = xcv_n; Bv = Bv_n; Cv = Cv_n;
    }
}

// ---- mean over L -> layernorm -> classifier; one block per batch ----
__global__ __launch_bounds__(256) void head_kernel(
    const float* __restrict__ h, const float* __restrict__ fn_w,
    const float* __restrict__ fn_b, const float* __restrict__ cls_w,
    const float* __restrict__ cls_b, float* __restrict__ out)
{
    int b = blockIdx.x, t = threadIdx.x;
    const float* hp = h + (size_t)b * L_ * DM + t;
    float s = 0.f;
    for (int l = 0; l < L_; ++l) s += hp[(size_t)l * DM];
    s *= (1.f / L_);
    float a = s, q = s * s;
    block_reduce2(a, q);
    float mu = a * (1.f / DM);
    float var = q * (1.f / DM) - mu * mu;
    float v = (s - mu) * rsqrtf(var + 1e-5f) * fn_w[t] + fn_b[t];
    __shared__ float pooled[DM];
    pooled[t] = v;
    __syncthreads();
    if (t < 10) {
        float acc = cls_b[t];
        for (int d2 = 0; d2 < DM; ++d2)
            acc = fmaf(pooled[d2], cls_w[t * DM + d2], acc);
        out[b * 10 + t] = acc;
    }
}

extern "C" void kernel_launch(void* const* d_in, const int* in_sizes, int n_in,
                              void* d_out, int out_size, void* d_ws, size_t ws_size,
                              hipStream_t stream)
{
    const float* x    = (const float*)d_in[0];
    const float* ipw  = (const float*)d_in[1];
    const float* ipb  = (const float*)d_in[2];
    const float* inw  = (const float*)d_in[3];
    const float* cw   = (const float*)d_in[4];
    const float* cb   = (const float*)d_in[5];
    const float* xpw  = (const float*)d_in[6];
    const float* dtw  = (const float*)d_in[7];
    const float* dtb  = (const float*)d_in[8];
    const float* alog = (const float*)d_in[9];
    const float* dsk  = (const float*)d_in[10];
    const float* opw  = (const float*)d_in[11];
    const float* lnw  = (const float*)d_in[12];
    const float* lnb  = (const float*)d_in[13];
    const float* fnw  = (const float*)d_in[14];
    const float* fnb  = (const float*)d_in[15];
    const float* clw  = (const float*)d_in[16];
    const float* clb  = (const float*)d_in[17];

    // workspace layout (floats); y aliases delta (safe: y[b,l,d] written only
    // after the last read of delta[b,l,d] within its owning lane group)
    float* ws    = (float*)d_ws;
    float* hbuf  = ws;                          // B*L*DM      = 1,048,576
    float* lnbuf = hbuf  + (size_t)B_ * L_ * DM;   // 1,048,576
    float* xzbuf = lnbuf + (size_t)B_ * L_ * DM;   // B*L*2*DIN = 4,194,304
    float* xcbuf = xzbuf + (size_t)B_ * L_ * 2 * DIN; // B*L*DIN = 2,097,152
    float* dbcbuf = xcbuf + (size_t)B_ * L_ * DIN;    // B*L*48  =   196,608
    float* dlbuf = dbcbuf + (size_t)B_ * L_ * 48;     // B*L*DIN = 2,097,152
    float* ybuf  = dlbuf;                             // aliased

    const int BL = B_ * L_;                       // 4096

    input_proj_kernel<<<BL * DM / 256, 256, 0, stream>>>(x, ipw, ipb, hbuf);

    for (int i = 0; i < 4; ++i) {
        ln_kernel<<<BL, 256, 0, stream>>>(hbuf, lnw + i * DM, lnb + i * DM, lnbuf);
        // xz = ln @ in_w^T   [4096,1024]
        gemm_tn<<<dim3(2 * DIN / 64, BL / 64), 256, 0, stream>>>(
            lnbuf, inw + (size_t)i * 2 * DIN * DM, xzbuf, BL, 2 * DIN, DM, 0);
        conv_silu_kernel<<<BL * DIN / 256, 256, 0, stream>>>(
            xzbuf, cw + i * DIN * 4, cb + i * DIN, xcbuf);
        // dbc = xc @ xp_w^T  [4096,48]
        gemm_tn<<<dim3(1, BL / 64), 256, 0, stream>>>(
            xcbuf, xpw + (size_t)i * 48 * DIN, dbcbuf, BL, 48, DIN, 0);
        dt_kernel<<<BL * DIN / 256, 256, 0, stream>>>(
            dbcbuf, dtw + i * DIN * DTR, dtb + i * DIN, dlbuf);
        scan_kernel<<<dim3(DIN / 16, B_), 256, 0, stream>>>(
            dlbuf, dbcbuf, xcbuf, xzbuf, alog + i * DIN * NST, dsk + i * DIN, ybuf);
        // h += y @ out_w^T   [4096,256]
        gemm_tn<<<dim3(DM / 64, BL / 64), 256, 0, stream>>>(
            ybuf, opw + (size_t)i * DM * DIN, hbuf, BL, DM, DIN, 1);
    }

    head_kernel<<<B_, 256, 0, stream>>>(hbuf, fnw, fnb, clw, clb, (float*)d_out);
}

// Round 2
// 910.222 us; speedup vs baseline: 3.2534x; 3.2534x over previous
//
#include <hip/hip_runtime.h>
#include <math.h>

#define B_ 4
#define L_ 1024
#define DM 256
#define DIN 512
#define NST 16
#define DTR 16
#define CHK 16          // number of chunks over L
#define CT (L_ / CHK)   // chunk length = 64

__device__ __forceinline__ float softplusf(float x) {
    return (x > 20.f) ? x : log1pf(__expf(x));
}
__device__ __forceinline__ float siluf(float x) {
    return x / (1.f + __expf(-x));
}

// two-value block reduction (sum) over 256 threads = 4 waves
__device__ __forceinline__ void block_reduce2(float& a, float& q) {
    #pragma unroll
    for (int off = 32; off > 0; off >>= 1) {
        a += __shfl_down(a, off);
        q += __shfl_down(q, off);
    }
    __shared__ float sa[4], sq[4];
    int lane = threadIdx.x & 63, w = threadIdx.x >> 6;
    if (lane == 0) { sa[w] = a; sq[w] = q; }
    __syncthreads();
    a = sa[0] + sa[1] + sa[2] + sa[3];
    q = sq[0] + sq[1] + sq[2] + sq[3];
}

// ---- input projection: h0[b,l,d] = bias[d] + sum_c x[b,c,l] * W[d,c] ----
__global__ __launch_bounds__(256) void input_proj_kernel(
    const float* __restrict__ x, const float* __restrict__ W,
    const float* __restrict__ bias, float* __restrict__ h0)
{
    int idx = blockIdx.x * 256 + threadIdx.x;     // B*L*DM, d fastest
    int d = idx & (DM - 1);
    int bl = idx >> 8;
    int l = bl & (L_ - 1);
    int b = bl >> 10;
    const float* xb = x + (size_t)b * 3 * L_;
    float acc = bias[d];
    acc = fmaf(xb[0 * L_ + l], W[d * 3 + 0], acc);
    acc = fmaf(xb[1 * L_ + l], W[d * 3 + 1], acc);
    acc = fmaf(xb[2 * L_ + l], W[d * 3 + 2], acc);
    h0[idx] = acc;
}

// ---- layernorm over last dim (256), one block per (b,l) row ----
__global__ __launch_bounds__(256) void ln_kernel(
    const float* __restrict__ x, const float* __restrict__ w,
    const float* __restrict__ bb, float* __restrict__ o)
{
    int row = blockIdx.x;
    int t = threadIdx.x;
    float v = x[(size_t)row * DM + t];
    float a = v, q = v * v;
    block_reduce2(a, q);
    float mu = a * (1.f / DM);
    float var = q * (1.f / DM) - mu * mu;
    o[(size_t)row * DM + t] = (v - mu) * rsqrtf(var + 1e-5f) * w[t] + bb[t];
}

// ---- GEMM: C[M,N] (+)= A[M,K] @ W[N,K]^T ; 64x64 tile, 256 thr, 4x4/thr ----
__global__ __launch_bounds__(256) void gemm_tn(
    const float* __restrict__ A, const float* __restrict__ W,
    float* C, int M, int N, int K, int accumulate)
{
    __shared__ float As[16][68];
    __shared__ float Ws[16][68];
    const int tx = threadIdx.x & 15;
    const int ty = threadIdx.x >> 4;
    const int m0 = blockIdx.y * 64;
    const int n0 = blockIdx.x * 64;
    const int lr = threadIdx.x >> 2;         // 0..63
    const int lk = (threadIdx.x & 3) * 4;    // 0,4,8,12
    float acc[4][4] = {};
    for (int k0 = 0; k0 < K; k0 += 16) {
        float4 av = *(const float4*)(A + (size_t)(m0 + lr) * K + (k0 + lk));
        int wn = n0 + lr;
        float4 wv = make_float4(0.f, 0.f, 0.f, 0.f);
        if (wn < N) wv = *(const float4*)(W + (size_t)wn * K + (k0 + lk));
        As[lk + 0][lr] = av.x; As[lk + 1][lr] = av.y;
        As[lk + 2][lr] = av.z; As[lk + 3][lr] = av.w;
        Ws[lk + 0][lr] = wv.x; Ws[lk + 1][lr] = wv.y;
        Ws[lk + 2][lr] = wv.z; Ws[lk + 3][lr] = wv.w;
        __syncthreads();
        #pragma unroll
        for (int k = 0; k < 16; ++k) {
            float4 a4 = *(const float4*)&As[k][ty * 4];
            float4 w4 = *(const float4*)&Ws[k][tx * 4];
            float ar[4] = {a4.x, a4.y, a4.z, a4.w};
            float wr[4] = {w4.x, w4.y, w4.z, w4.w};
            #pragma unroll
            for (int i = 0; i < 4; ++i)
                #pragma unroll
                for (int j = 0; j < 4; ++j)
                    acc[i][j] = fmaf(ar[i], wr[j], acc[i][j]);
        }
        __syncthreads();
    }
    #pragma unroll
    for (int i = 0; i < 4; ++i) {
        int m = m0 + ty * 4 + i;
        int n = n0 + tx * 4;
        if (n + 3 < N) {
            float* cp = C + (size_t)m * N + n;
            float4 cv;
            if (accumulate) {
                cv = *(const float4*)cp;
                cv.x += acc[i][0]; cv.y += acc[i][1];
                cv.z += acc[i][2]; cv.w += acc[i][3];
            } else {
                cv = make_float4(acc[i][0], acc[i][1], acc[i][2], acc[i][3]);
            }
            *(float4*)cp = cv;
        }
    }
}

// ---- causal depthwise conv (k=4) + silu: xz[:, :, :512] -> xc ----
__global__ __launch_bounds__(256) void conv_silu_kernel(
    const float* __restrict__ xz, const float* __restrict__ cw,
    const float* __restrict__ cb, float* __restrict__ xc)
{
    int idx = blockIdx.x * 256 + threadIdx.x;   // B*L*DIN, d fastest
    int d = idx & (DIN - 1);
    int bl = idx >> 9;
    int l = bl & (L_ - 1);
    int b = bl >> 10;
    float acc = cb[d];
    #pragma unroll
    for (int k = 0; k < 4; ++k) {
        int ls = l - 3 + k;
        if (ls >= 0)
            acc = fmaf(xz[((size_t)(b * L_ + ls)) * (2 * DIN) + d], cw[d * 4 + k], acc);
    }
    xc[idx] = siluf(acc);
}

// ---- delta[b,l,d] = softplus(dbc[b,l,0:16] . dt_w[d,:] + dt_b[d]) ----
__global__ __launch_bounds__(256) void dt_kernel(
    const float* __restrict__ dbc, const float* __restrict__ dt_w,
    const float* __restrict__ dt_b, float* __restrict__ delta)
{
    int idx = blockIdx.x * 256 + threadIdx.x;   // B*L*DIN, d fastest
    int d = idx & (DIN - 1);
    int bl = idx >> 9;
    const float* dr = dbc + (size_t)bl * 48;
    const float* wr = dt_w + d * DTR;
    float acc = dt_b[d];
    #pragma unroll
    for (int r = 0; r < DTR; ++r)
        acc = fmaf(dr[r], wr[r], acc);
    delta[idx] = softplusf(acc);
}

// ==== chunked selective scan ====
// recurrence per (b,d,n): h_l = dA_l*h_{l-1} + dBu_l   (linear -> chunkable)
// pass 1: per chunk c, compute P = prod(dA) and H = local scan (h_in = 0)
// pass 2 (fused in pass 3 prologue): h_in(c) = scan over chunk summaries
// pass 3: re-scan own chunk from h_in, emit gated y
// block = 256 = 16 d-channels x 16 states; lane = dl*16 + n

__global__ __launch_bounds__(256) void scan_summary_kernel(
    const float* __restrict__ delta, const float* __restrict__ dbc,
    const float* __restrict__ xc, const float* __restrict__ A_log,
    float* __restrict__ Psum, float* __restrict__ Hsum)
{
    const int n = threadIdx.x & 15;
    const int dl = threadIdx.x >> 4;
    const int d = blockIdx.x * 16 + dl;
    const int c = blockIdx.y;
    const int b = blockIdx.z;
    const float A = -__expf(A_log[d * NST + n]);
    const int l0 = c * CT;
    const float* dptr = delta + ((size_t)b * L_ + l0) * DIN + d;
    const float* xcp  = xc    + ((size_t)b * L_ + l0) * DIN + d;
    const float* bcp  = dbc   + ((size_t)b * L_ + l0) * 48;

    float h = 0.f, P = 1.f;
    #pragma unroll 4
    for (int t = 0; t < CT; ++t) {
        float dlt = dptr[(size_t)t * DIN];
        float xcv = xcp[(size_t)t * DIN];
        float Bv  = bcp[(size_t)t * 48 + DTR + n];
        float dA = __expf(dlt * A);
        h = fmaf(dA, h, dlt * Bv * xcv);
        P *= dA;
    }
    size_t o = (((size_t)b * CHK + c) * DIN + d) * NST + n;
    Psum[o] = P;
    Hsum[o] = h;
}

// NOTE: delta and y alias (y[b,l,d] overwrites delta[b,l,d] after its last
// read within this block's chunk) -> intentionally NOT __restrict__.
__global__ __launch_bounds__(256) void scan_apply_kernel(
    const float* delta, const float* __restrict__ dbc,
    const float* __restrict__ xc, const float* __restrict__ xz,
    const float* __restrict__ A_log, const float* __restrict__ Dskip,
    const float* __restrict__ Psum, const float* __restrict__ Hsum,
    float* y)
{
    const int n = threadIdx.x & 15;
    const int dl = threadIdx.x >> 4;
    const int d = blockIdx.x * 16 + dl;
    const int c = blockIdx.y;
    const int b = blockIdx.z;
    const float A = -__expf(A_log[d * NST + n]);
    const float Dsk = Dskip[d];
    const int l0 = c * CT;
    const float* dptr = delta + ((size_t)b * L_ + l0) * DIN + d;
    const float* xcp  = xc    + ((size_t)b * L_ + l0) * DIN + d;
    const float* zp   = xz    + ((size_t)b * L_ + l0) * (2 * DIN) + DIN + d;
    const float* bcp  = dbc   + ((size_t)b * L_ + l0) * 48;
    float* yp         = y     + ((size_t)b * L_ + l0) * DIN + d;

    // h_in for this chunk from the summaries of chunks 0..c-1
    float h = 0.f;
    {
        size_t base = (((size_t)b * CHK) * DIN + d) * NST + n;
        for (int cc = 0; cc < c; ++cc) {
            size_t o = base + (size_t)cc * DIN * NST;
            h = fmaf(Psum[o], h, Hsum[o]);
        }
    }

    #pragma unroll 2
    for (int t = 0; t < CT; ++t) {
        float dlt = dptr[(size_t)t * DIN];
        float xcv = xcp[(size_t)t * DIN];
        float Bv  = bcp[(size_t)t * 48 + DTR + n];
        float Cv  = bcp[(size_t)t * 48 + DTR + NST + n];
        float dA = __expf(dlt * A);
        h = fmaf(dA, h, dlt * Bv * xcv);
        float p = h * Cv;
        p += __shfl_xor(p, 1);
        p += __shfl_xor(p, 2);
        p += __shfl_xor(p, 4);
        p += __shfl_xor(p, 8);
        if (n == 0) {
            float zv = zp[(size_t)t * (2 * DIN)];
            yp[(size_t)t * DIN] = (p + xcv * Dsk) * siluf(zv);
        }
    }
}

// ---- mean over L -> layernorm -> classifier; one block per batch ----
__global__ __launch_bounds__(256) void head_kernel(
    const float* __restrict__ h, const float* __restrict__ fn_w,
    const float* __restrict__ fn_b, const float* __restrict__ cls_w,
    const float* __restrict__ cls_b, float* __restrict__ out)
{
    int b = blockIdx.x, t = threadIdx.x;
    const float* hp = h + (size_t)b * L_ * DM + t;
    float s = 0.f;
    for (int l = 0; l < L_; ++l) s += hp[(size_t)l * DM];
    s *= (1.f / L_);
    float a = s, q = s * s;
    block_reduce2(a, q);
    float mu = a * (1.f / DM);
    float var = q * (1.f / DM) - mu * mu;
    float v = (s - mu) * rsqrtf(var + 1e-5f) * fn_w[t] + fn_b[t];
    __shared__ float pooled[DM];
    pooled[t] = v;
    __syncthreads();
    if (t < 10) {
        float acc = cls_b[t];
        for (int d2 = 0; d2 < DM; ++d2)
            acc = fmaf(pooled[d2], cls_w[t * DM + d2], acc);
        out[b * 10 + t] = acc;
    }
}

extern "C" void kernel_launch(void* const* d_in, const int* in_sizes, int n_in,
                              void* d_out, int out_size, void* d_ws, size_t ws_size,
                              hipStream_t stream)
{
    const float* x    = (const float*)d_in[0];
    const float* ipw  = (const float*)d_in[1];
    const float* ipb  = (const float*)d_in[2];
    const float* inw  = (const float*)d_in[3];
    const float* cw   = (const float*)d_in[4];
    const float* cb   = (const float*)d_in[5];
    const float* xpw  = (const float*)d_in[6];
    const float* dtw  = (const float*)d_in[7];
    const float* dtb  = (const float*)d_in[8];
    const float* alog = (const float*)d_in[9];
    const float* dsk  = (const float*)d_in[10];
    const float* opw  = (const float*)d_in[11];
    const float* lnw  = (const float*)d_in[12];
    const float* lnb  = (const float*)d_in[13];
    const float* fnw  = (const float*)d_in[14];
    const float* fnb  = (const float*)d_in[15];
    const float* clw  = (const float*)d_in[16];
    const float* clb  = (const float*)d_in[17];

    // workspace layout (floats)
    // - y aliases delta (y[b,l,d] written after last read of delta[b,l,d])
    // - Psum/Hsum alias lnbuf (lnbuf dead after in_proj GEMM consumes it;
    //   exactly 2 x 524288 floats = lnbuf's 1,048,576 floats)
    float* ws    = (float*)d_ws;
    float* hbuf  = ws;                                // B*L*DM   = 1,048,576
    float* lnbuf = hbuf  + (size_t)B_ * L_ * DM;      // 1,048,576
    float* xzbuf = lnbuf + (size_t)B_ * L_ * DM;      // B*L*2*DIN = 4,194,304
    float* xcbuf = xzbuf + (size_t)B_ * L_ * 2 * DIN; // B*L*DIN  = 2,097,152
    float* dbcbuf = xcbuf + (size_t)B_ * L_ * DIN;    // B*L*48   =   196,608
    float* dlbuf = dbcbuf + (size_t)B_ * L_ * 48;     // B*L*DIN  = 2,097,152
    float* ybuf  = dlbuf;                             // aliased
    float* Psum  = lnbuf;                             // B*CHK*DIN*NST = 524,288
    float* Hsum  = Psum + (size_t)B_ * CHK * DIN * NST;

    const int BL = B_ * L_;                           // 4096

    input_proj_kernel<<<BL * DM / 256, 256, 0, stream>>>(x, ipw, ipb, hbuf);

    for (int i = 0; i < 4; ++i) {
        ln_kernel<<<BL, 256, 0, stream>>>(hbuf, lnw + i * DM, lnb + i * DM, lnbuf);
        // xz = ln @ in_w^T   [4096,1024]
        gemm_tn<<<dim3(2 * DIN / 64, BL / 64), 256, 0, stream>>>(
            lnbuf, inw + (size_t)i * 2 * DIN * DM, xzbuf, BL, 2 * DIN, DM, 0);
        conv_silu_kernel<<<BL * DIN / 256, 256, 0, stream>>>(
            xzbuf, cw + i * DIN * 4, cb + i * DIN, xcbuf);
        // dbc = xc @ xp_w^T  [4096,48]
        gemm_tn<<<dim3(1, BL / 64), 256, 0, stream>>>(
            xcbuf, xpw + (size_t)i * 48 * DIN, dbcbuf, BL, 48, DIN, 0);
        dt_kernel<<<BL * DIN / 256, 256, 0, stream>>>(
            dbcbuf, dtw + i * DIN * DTR, dtb + i * DIN, dlbuf);
        // chunked scan: summaries then apply
        scan_summary_kernel<<<dim3(DIN / 16, CHK, B_), 256, 0, stream>>>(
            dlbuf, dbcbuf, xcbuf, alog + i * DIN * NST, Psum, Hsum);
        scan_apply_kernel<<<dim3(DIN / 16, CHK, B_), 256, 0, stream>>>(
            dlbuf, dbcbuf, xcbuf, xzbuf, alog + i * DIN * NST, dsk + i * DIN,
            Psum, Hsum, ybuf);
        // h += y @ out_w^T   [4096,256]
        gemm_tn<<<dim3(DM / 64, BL / 64), 256, 0, stream>>>(
            ybuf, opw + (size_t)i * DM * DIN, hbuf, BL, DM, DIN, 1);
    }

    head_kernel<<<B_, 256, 0, stream>>>(hbuf, fnw, fnb, clw, clb, (float*)d_out);
}

// Round 3
// 749.516 us; speedup vs baseline: 3.9509x; 1.2144x over previous
//
#include <hip/hip_runtime.h>
#include <math.h>

#define B_ 4
#define L_ 1024
#define DM 256
#define DIN 512
#define NST 16
#define DTR 16
#define CHK 32          // number of chunks over L
#define CT (L_ / CHK)   // chunk length = 32

__device__ __forceinline__ float softplusf(float x) {
    return (x > 20.f) ? x : log1pf(__expf(x));
}
__device__ __forceinline__ float siluf(float x) {
    return x / (1.f + __expf(-x));
}

// two-value block reduction (sum) over 256 threads = 4 waves
__device__ __forceinline__ void block_reduce2(float& a, float& q) {
    #pragma unroll
    for (int off = 32; off > 0; off >>= 1) {
        a += __shfl_down(a, off);
        q += __shfl_down(q, off);
    }
    __shared__ float sa[4], sq[4];
    int lane = threadIdx.x & 63, w = threadIdx.x >> 6;
    if (lane == 0) { sa[w] = a; sq[w] = q; }
    __syncthreads();
    a = sa[0] + sa[1] + sa[2] + sa[3];
    q = sq[0] + sq[1] + sq[2] + sq[3];
}

// ---- input projection: h0[b,l,d] = bias[d] + sum_c x[b,c,l] * W[d,c] ----
__global__ __launch_bounds__(256) void input_proj_kernel(
    const float* __restrict__ x, const float* __restrict__ W,
    const float* __restrict__ bias, float* __restrict__ h0)
{
    int idx = blockIdx.x * 256 + threadIdx.x;     // B*L*DM, d fastest
    int d = idx & (DM - 1);
    int bl = idx >> 8;
    int l = bl & (L_ - 1);
    int b = bl >> 10;
    const float* xb = x + (size_t)b * 3 * L_;
    float acc = bias[d];
    acc = fmaf(xb[0 * L_ + l], W[d * 3 + 0], acc);
    acc = fmaf(xb[1 * L_ + l], W[d * 3 + 1], acc);
    acc = fmaf(xb[2 * L_ + l], W[d * 3 + 2], acc);
    h0[idx] = acc;
}

// ---- layernorm over last dim (256), one block per (b,l) row ----
__global__ __launch_bounds__(256) void ln_kernel(
    const float* __restrict__ x, const float* __restrict__ w,
    const float* __restrict__ bb, float* __restrict__ o)
{
    int row = blockIdx.x;
    int t = threadIdx.x;
    float v = x[(size_t)row * DM + t];
    float a = v, q = v * v;
    block_reduce2(a, q);
    float mu = a * (1.f / DM);
    float var = q * (1.f / DM) - mu * mu;
    o[(size_t)row * DM + t] = (v - mu) * rsqrtf(var + 1e-5f) * w[t] + bb[t];
}

// ---- GEMM: C[M,N] (+)= A[M,K] @ W[N,K]^T ; A row stride = lda ----
__global__ __launch_bounds__(256) void gemm_tn(
    const float* __restrict__ A, const float* __restrict__ W,
    float* C, int M, int N, int K, int lda, int accumulate)
{
    __shared__ float As[16][68];
    __shared__ float Ws[16][68];
    const int tx = threadIdx.x & 15;
    const int ty = threadIdx.x >> 4;
    const int m0 = blockIdx.y * 64;
    const int n0 = blockIdx.x * 64;
    const int lr = threadIdx.x >> 2;         // 0..63
    const int lk = (threadIdx.x & 3) * 4;    // 0,4,8,12
    float acc[4][4] = {};
    for (int k0 = 0; k0 < K; k0 += 16) {
        float4 av = *(const float4*)(A + (size_t)(m0 + lr) * lda + (k0 + lk));
        int wn = n0 + lr;
        float4 wv = make_float4(0.f, 0.f, 0.f, 0.f);
        if (wn < N) wv = *(const float4*)(W + (size_t)wn * K + (k0 + lk));
        As[lk + 0][lr] = av.x; As[lk + 1][lr] = av.y;
        As[lk + 2][lr] = av.z; As[lk + 3][lr] = av.w;
        Ws[lk + 0][lr] = wv.x; Ws[lk + 1][lr] = wv.y;
        Ws[lk + 2][lr] = wv.z; Ws[lk + 3][lr] = wv.w;
        __syncthreads();
        #pragma unroll
        for (int k = 0; k < 16; ++k) {
            float4 a4 = *(const float4*)&As[k][ty * 4];
            float4 w4 = *(const float4*)&Ws[k][tx * 4];
            float ar[4] = {a4.x, a4.y, a4.z, a4.w};
            float wr[4] = {w4.x, w4.y, w4.z, w4.w};
            #pragma unroll
            for (int i = 0; i < 4; ++i)
                #pragma unroll
                for (int j = 0; j < 4; ++j)
                    acc[i][j] = fmaf(ar[i], wr[j], acc[i][j]);
        }
        __syncthreads();
    }
    #pragma unroll
    for (int i = 0; i < 4; ++i) {
        int m = m0 + ty * 4 + i;
        int n = n0 + tx * 4;
        if (n + 3 < N) {
            float* cp = C + (size_t)m * N + n;
            float4 cv;
            if (accumulate) {
                cv = *(const float4*)cp;
                cv.x += acc[i][0]; cv.y += acc[i][1];
                cv.z += acc[i][2]; cv.w += acc[i][3];
            } else {
                cv = make_float4(acc[i][0], acc[i][1], acc[i][2], acc[i][3]);
            }
            *(float4*)cp = cv;
        }
    }
}

// ---- causal depthwise conv (k=4) + silu: xz[:, :, :512] -> xc ----
__global__ __launch_bounds__(256) void conv_silu_kernel(
    const float* __restrict__ xz, const float* __restrict__ cw,
    const float* __restrict__ cb, float* __restrict__ xc)
{
    int idx = blockIdx.x * 256 + threadIdx.x;   // B*L*DIN, d fastest
    int d = idx & (DIN - 1);
    int bl = idx >> 9;
    int l = bl & (L_ - 1);
    int b = bl >> 10;
    float acc = cb[d];
    #pragma unroll
    for (int k = 0; k < 4; ++k) {
        int ls = l - 3 + k;
        if (ls >= 0)
            acc = fmaf(xz[((size_t)(b * L_ + ls)) * (2 * DIN) + d], cw[d * 4 + k], acc);
    }
    xc[idx] = siluf(acc);
}

// ---- delta[b,l,d] = softplus(dbc[b,l,0:16] . dt_w[d,:] + dt_b[d]) ----
__global__ __launch_bounds__(256) void dt_kernel(
    const float* __restrict__ dbc, const float* __restrict__ dt_w,
    const float* __restrict__ dt_b, float* __restrict__ delta)
{
    int idx = blockIdx.x * 256 + threadIdx.x;   // B*L*DIN, d fastest
    int d = idx & (DIN - 1);
    int bl = idx >> 9;
    const float* dr = dbc + (size_t)bl * 48;
    const float* wr = dt_w + d * DTR;
    float acc = dt_b[d];
    #pragma unroll
    for (int r = 0; r < DTR; ++r)
        acc = fmaf(dr[r], wr[r], acc);
    delta[idx] = softplusf(acc);
}

// ==== chunked selective scan, thread-per-channel (16 states in registers) ====
// thread = (b, chunk c, channel d); lane index = d (coalesced delta/xc/y).
// B_t/C_t rows of dbc are block-uniform -> scalar loads, zero VALU cost.
// pass 1 (summary): local scan h[16] from 0, plus ssum = sum(delta) so the
//   chunk decay is P_n = exp(A_n * ssum) (math-identical to prod of exps).
// pass 2 (prefix): tiny serial scan over CHK chunk summaries, in-place:
//   H[c] <- h_in(c).
// pass 3 (apply): re-scan own chunk from h_in, emit gated y.

__global__ __launch_bounds__(256) void scan_summary_kernel(
    const float* __restrict__ delta, const float* __restrict__ dbc,
    const float* __restrict__ xc, const float* __restrict__ A_log,
    float* __restrict__ S, float* __restrict__ H)
{
    const int d = blockIdx.x * 256 + threadIdx.x;
    const int c = blockIdx.y;
    const int b = blockIdx.z;
    float A[NST];
    #pragma unroll
    for (int j = 0; j < NST; ++j) A[j] = -__expf(A_log[d * NST + j]);
    const int l0 = c * CT;
    const float* dp = delta + ((size_t)(b * L_ + l0)) * DIN + d;
    const float* xp = xc    + ((size_t)(b * L_ + l0)) * DIN + d;
    const float* bc = dbc   + ((size_t)(b * L_ + l0)) * 48 + DTR;
    float h[NST];
    #pragma unroll
    for (int j = 0; j < NST; ++j) h[j] = 0.f;
    float ssum = 0.f;
    #pragma unroll 4
    for (int t = 0; t < CT; ++t) {
        float dlt = dp[t * DIN];
        float xcv = xp[t * DIN];
        float t0 = dlt * xcv;
        ssum += dlt;
        const float* br = bc + t * 48;   // block-uniform address
        #pragma unroll
        for (int j = 0; j < NST; ++j) {
            float dA = __expf(A[j] * dlt);
            h[j] = fmaf(dA, h[j], t0 * br[j]);
        }
    }
    S[((size_t)b * CHK + c) * DIN + d] = ssum;
    float* Hp = H + (((size_t)b * CHK + c) * DIN + d) * NST;
    #pragma unroll
    for (int j = 0; j < NST; j += 4)
        *(float4*)(Hp + j) = make_float4(h[j], h[j + 1], h[j + 2], h[j + 3]);
}

__global__ __launch_bounds__(256) void scan_prefix_kernel(
    const float* __restrict__ S, float* __restrict__ H,
    const float* __restrict__ A_log)
{
    int idx = blockIdx.x * 256 + threadIdx.x;  // B*DIN*NST, n fastest
    int n = idx & (NST - 1);
    int dn = idx >> 4;
    int d = dn & (DIN - 1);
    int b = dn >> 9;
    float A = -__expf(A_log[d * NST + n]);
    float hprev = 0.f;
    const float* Sp = S + (size_t)b * CHK * DIN + d;
    float* Hp = H + ((size_t)b * CHK * DIN + d) * NST + n;
    for (int c = 0; c < CHK; ++c) {
        float Hc = Hp[(size_t)c * DIN * NST];
        float Sc = Sp[(size_t)c * DIN];
        Hp[(size_t)c * DIN * NST] = hprev;                  // h_in(c)
        hprev = fmaf(__expf(A * Sc), hprev, Hc);
    }
}

// y is written into the dead xh half of xz (rows stride 2*DIN); z is the live
// upper half. The two restrict pointers point into the same buffer but their
// accessed element sets are disjoint (d < 512 vs d >= 512) -> legal restrict.
__global__ __launch_bounds__(256) void scan_apply_kernel(
    const float* __restrict__ delta, const float* __restrict__ dbc,
    const float* __restrict__ xc, const float* __restrict__ z,
    const float* __restrict__ A_log, const float* __restrict__ Dskip,
    const float* __restrict__ H, float* __restrict__ y)
{
    const int d = blockIdx.x * 256 + threadIdx.x;
    const int c = blockIdx.y;
    const int b = blockIdx.z;
    float A[NST];
    #pragma unroll
    for (int j = 0; j < NST; ++j) A[j] = -__expf(A_log[d * NST + j]);
    const float Dsk = Dskip[d];
    const int l0 = c * CT;
    const float* dp = delta + ((size_t)(b * L_ + l0)) * DIN + d;
    const float* xp = xc    + ((size_t)(b * L_ + l0)) * DIN + d;
    const float* bc = dbc   + ((size_t)(b * L_ + l0)) * 48 + DTR;
    const float* zp = z     + ((size_t)(b * L_ + l0)) * (2 * DIN) + DIN + d;
    float* yp       = y     + ((size_t)(b * L_ + l0)) * (2 * DIN) + d;

    const float* Hp = H + (((size_t)b * CHK + c) * DIN + d) * NST;
    float h[NST];
    #pragma unroll
    for (int j = 0; j < NST; j += 4) {
        float4 hv = *(const float4*)(Hp + j);
        h[j] = hv.x; h[j + 1] = hv.y; h[j + 2] = hv.z; h[j + 3] = hv.w;
    }

    #pragma unroll 4
    for (int t = 0; t < CT; ++t) {
        float dlt = dp[t * DIN];
        float xcv = xp[t * DIN];
        float zv  = zp[t * (2 * DIN)];
        float t0 = dlt * xcv;
        const float* br = bc + t * 48;        // block-uniform address
        const float* cr = br + NST;
        float p = 0.f;
        #pragma unroll
        for (int j = 0; j < NST; ++j) {
            float dA = __expf(A[j] * dlt);
            h[j] = fmaf(dA, h[j], t0 * br[j]);
            p = fmaf(h[j], cr[j], p);
        }
        yp[t * (2 * DIN)] = (p + xcv * Dsk) * siluf(zv);
    }
}

// ---- mean over L -> layernorm -> classifier; one block per batch ----
__global__ __launch_bounds__(256) void head_kernel(
    const float* __restrict__ h, const float* __restrict__ fn_w,
    const float* __restrict__ fn_b, const float* __restrict__ cls_w,
    const float* __restrict__ cls_b, float* __restrict__ out)
{
    int b = blockIdx.x, t = threadIdx.x;
    const float* hp = h + (size_t)b * L_ * DM + t;
    float s = 0.f;
    for (int l = 0; l < L_; ++l) s += hp[(size_t)l * DM];
    s *= (1.f / L_);
    float a = s, q = s * s;
    block_reduce2(a, q);
    float mu = a * (1.f / DM);
    float var = q * (1.f / DM) - mu * mu;
    float v = (s - mu) * rsqrtf(var + 1e-5f) * fn_w[t] + fn_b[t];
    __shared__ float pooled[DM];
    pooled[t] = v;
    __syncthreads();
    if (t < 10) {
        float acc = cls_b[t];
        for (int d2 = 0; d2 < DM; ++d2)
            acc = fmaf(pooled[d2], cls_w[t * DM + d2], acc);
        out[b * 10 + t] = acc;
    }
}

extern "C" void kernel_launch(void* const* d_in, const int* in_sizes, int n_in,
                              void* d_out, int out_size, void* d_ws, size_t ws_size,
                              hipStream_t stream)
{
    const float* x    = (const float*)d_in[0];
    const float* ipw  = (const float*)d_in[1];
    const float* ipb  = (const float*)d_in[2];
    const float* inw  = (const float*)d_in[3];
    const float* cw   = (const float*)d_in[4];
    const float* cb   = (const float*)d_in[5];
    const float* xpw  = (const float*)d_in[6];
    const float* dtw  = (const float*)d_in[7];
    const float* dtb  = (const float*)d_in[8];
    const float* alog = (const float*)d_in[9];
    const float* dsk  = (const float*)d_in[10];
    const float* opw  = (const float*)d_in[11];
    const float* lnw  = (const float*)d_in[12];
    const float* lnb  = (const float*)d_in[13];
    const float* fnw  = (const float*)d_in[14];
    const float* fnb  = (const float*)d_in[15];
    const float* clw  = (const float*)d_in[16];
    const float* clb  = (const float*)d_in[17];

    // workspace layout (floats)
    // - H aliases lnbuf: lnbuf dead after in_proj GEMM; B*CHK*DIN*NST =
    //   1,048,576 floats = exactly lnbuf's extent.
    // - y lives in the xh half of xzbuf (dead after conv_silu).
    float* ws    = (float*)d_ws;
    float* hbuf  = ws;                                // B*L*DM   = 1,048,576
    float* lnbuf = hbuf  + (size_t)B_ * L_ * DM;      // 1,048,576
    float* xzbuf = lnbuf + (size_t)B_ * L_ * DM;      // B*L*2*DIN = 4,194,304
    float* xcbuf = xzbuf + (size_t)B_ * L_ * 2 * DIN; // B*L*DIN  = 2,097,152
    float* dbcbuf = xcbuf + (size_t)B_ * L_ * DIN;    // B*L*48   =   196,608
    float* dlbuf = dbcbuf + (size_t)B_ * L_ * 48;     // B*L*DIN  = 2,097,152
    float* Sbuf  = dlbuf + (size_t)B_ * L_ * DIN;     // B*CHK*DIN =   65,536
    float* Hbuf  = lnbuf;                             // aliased
    float* ybuf  = xzbuf;                             // y in xh half, stride 2*DIN

    const int BL = B_ * L_;                           // 4096

    input_proj_kernel<<<BL * DM / 256, 256, 0, stream>>>(x, ipw, ipb, hbuf);

    for (int i = 0; i < 4; ++i) {
        ln_kernel<<<BL, 256, 0, stream>>>(hbuf, lnw + i * DM, lnb + i * DM, lnbuf);
        // xz = ln @ in_w^T   [4096,1024]
        gemm_tn<<<dim3(2 * DIN / 64, BL / 64), 256, 0, stream>>>(
            lnbuf, inw + (size_t)i * 2 * DIN * DM, xzbuf, BL, 2 * DIN, DM, DM, 0);
        conv_silu_kernel<<<BL * DIN / 256, 256, 0, stream>>>(
            xzbuf, cw + i * DIN * 4, cb + i * DIN, xcbuf);
        // dbc = xc @ xp_w^T  [4096,48]
        gemm_tn<<<dim3(1, BL / 64), 256, 0, stream>>>(
            xcbuf, xpw + (size_t)i * 48 * DIN, dbcbuf, BL, 48, DIN, DIN, 0);
        dt_kernel<<<BL * DIN / 256, 256, 0, stream>>>(
            dbcbuf, dtw + i * DIN * DTR, dtb + i * DIN, dlbuf);
        // chunked scan: summary -> prefix -> apply
        scan_summary_kernel<<<dim3(DIN / 256, CHK, B_), 256, 0, stream>>>(
            dlbuf, dbcbuf, xcbuf, alog + i * DIN * NST, Sbuf, Hbuf);
        scan_prefix_kernel<<<B_ * DIN * NST / 256, 256, 0, stream>>>(
            Sbuf, Hbuf, alog + i * DIN * NST);
        scan_apply_kernel<<<dim3(DIN / 256, CHK, B_), 256, 0, stream>>>(
            dlbuf, dbcbuf, xcbuf, xzbuf, alog + i * DIN * NST, dsk + i * DIN,
            Hbuf, ybuf);
        // h += y @ out_w^T   [4096,256], y rows stride 2*DIN inside xz
        gemm_tn<<<dim3(DM / 64, BL / 64), 256, 0, stream>>>(
            ybuf, opw + (size_t)i * DM * DIN, hbuf, BL, DM, DIN, 2 * DIN, 1);
    }

    head_kernel<<<B_, 256, 0, stream>>>(hbuf, fnw, fnb, clw, clb, (float*)d_out);
}

// Round 4
// 597.007 us; speedup vs baseline: 4.9602x; 1.2555x over previous
//
#include <hip/hip_runtime.h>
#include <math.h>

#define B_ 4
#define L_ 1024
#define DM 256
#define DIN 512
#define NST 16
#define DTR 16
#define CHK 32          // number of chunks over L
#define CT (L_ / CHK)   // chunk length = 32

typedef short short8 __attribute__((ext_vector_type(8)));
typedef float float4v __attribute__((ext_vector_type(4)));

__device__ __forceinline__ float softplusf(float x) {
    return (x > 20.f) ? x : log1pf(__expf(x));
}
__device__ __forceinline__ float siluf(float x) {
    return x / (1.f + __expf(-x));
}
__device__ __forceinline__ unsigned short f2bf(float f) {  // RNE bf16
    unsigned int u = __float_as_uint(f);
    u = (u + 0x7fffu + ((u >> 16) & 1u)) >> 16;
    return (unsigned short)u;
}

// two-value block reduction (sum) over 256 threads = 4 waves
__device__ __forceinline__ void block_reduce2(float& a, float& q) {
    #pragma unroll
    for (int off = 32; off > 0; off >>= 1) {
        a += __shfl_down(a, off);
        q += __shfl_down(q, off);
    }
    __shared__ float sa[4], sq[4];
    int lane = threadIdx.x & 63, w = threadIdx.x >> 6;
    if (lane == 0) { sa[w] = a; sq[w] = q; }
    __syncthreads();
    a = sa[0] + sa[1] + sa[2] + sa[3];
    q = sq[0] + sq[1] + sq[2] + sq[3];
}

// ---- fp32 -> bf16 conversion (weights, once per launch) ----
__global__ __launch_bounds__(256) void f2bf_kernel(
    const float* __restrict__ in, unsigned short* __restrict__ out, int n)
{
    int i = blockIdx.x * 256 + threadIdx.x;
    if (i < n) out[i] = f2bf(in[i]);
}

// ---- input projection: h0[b,l,d] = bias[d] + sum_c x[b,c,l] * W[d,c] ----
__global__ __launch_bounds__(256) void input_proj_kernel(
    const float* __restrict__ x, const float* __restrict__ W,
    const float* __restrict__ bias, float* __restrict__ h0)
{
    int idx = blockIdx.x * 256 + threadIdx.x;     // B*L*DM, d fastest
    int d = idx & (DM - 1);
    int bl = idx >> 8;
    int l = bl & (L_ - 1);
    int b = bl >> 10;
    const float* xb = x + (size_t)b * 3 * L_;
    float acc = bias[d];
    acc = fmaf(xb[0 * L_ + l], W[d * 3 + 0], acc);
    acc = fmaf(xb[1 * L_ + l], W[d * 3 + 1], acc);
    acc = fmaf(xb[2 * L_ + l], W[d * 3 + 2], acc);
    h0[idx] = acc;
}

// ---- layernorm over last dim (256) -> bf16; one block per (b,l) row ----
__global__ __launch_bounds__(256) void ln_kernel(
    const float* __restrict__ x, const float* __restrict__ w,
    const float* __restrict__ bb, unsigned short* __restrict__ o)
{
    int row = blockIdx.x;
    int t = threadIdx.x;
    float v = x[(size_t)row * DM + t];
    float a = v, q = v * v;
    block_reduce2(a, q);
    float mu = a * (1.f / DM);
    float var = q * (1.f / DM) - mu * mu;
    o[(size_t)row * DM + t] = f2bf((v - mu) * rsqrtf(var + 1e-5f) * w[t] + bb[t]);
}

// ---- bf16 MFMA GEMM: C[M,N] (+)= A[M,K] @ W[N,K]^T  (fp32 accum/output) ----
// 64x64 tile, KT=64, 4 waves; wave w owns rows [w*16, w*16+16).
// Fragment layouts (16x16x32, HW-verified per guide):
//   A/B operand: lane holds row (lane&15), k = (lane>>4)*8 + j  (8 contig bf16)
//   C/D:         col = lane&15, row = (lane>>4)*4 + reg
__global__ __launch_bounds__(256) void gemm_bt_bf16(
    const unsigned short* __restrict__ A, const unsigned short* __restrict__ W,
    float* C, int M, int N, int K, int lda, int accumulate)
{
    __shared__ unsigned short As[64][72];
    __shared__ unsigned short Ws[64][72];
    const int tid = threadIdx.x;
    const int wave = tid >> 6;
    const int lane = tid & 63;
    const int m_l = lane & 15;
    const int q = lane >> 4;
    const int m0 = blockIdx.y * 64;
    const int n0 = blockIdx.x * 64;
    const int sr = tid >> 3;          // 0..31 staging row
    const int sc = (tid & 7) * 8;     // staging col (shorts)

    float4v acc[4];
    #pragma unroll
    for (int j = 0; j < 4; ++j) acc[j] = (float4v)(0.f);

    for (int k0 = 0; k0 < K; k0 += 64) {
        // stage A (64x64 bf16) and W (64x64 bf16)
        *(short8*)&As[sr][sc]      = *(const short8*)(A + (size_t)(m0 + sr) * lda + k0 + sc);
        *(short8*)&As[sr + 32][sc] = *(const short8*)(A + (size_t)(m0 + sr + 32) * lda + k0 + sc);
        short8 wz = (short8)0;
        int wn0 = n0 + sr, wn1 = n0 + sr + 32;
        *(short8*)&Ws[sr][sc]      = (wn0 < N) ? *(const short8*)(W + (size_t)wn0 * K + k0 + sc) : wz;
        *(short8*)&Ws[sr + 32][sc] = (wn1 < N) ? *(const short8*)(W + (size_t)wn1 * K + k0 + sc) : wz;
        __syncthreads();
        #pragma unroll
        for (int kk = 0; kk < 64; kk += 32) {
            short8 a = *(const short8*)&As[wave * 16 + m_l][kk + q * 8];
            #pragma unroll
            for (int j4 = 0; j4 < 4; ++j4) {
                short8 b = *(const short8*)&Ws[j4 * 16 + m_l][kk + q * 8];
                acc[j4] = __builtin_amdgcn_mfma_f32_16x16x32_bf16(a, b, acc[j4], 0, 0, 0);
            }
        }
        __syncthreads();
    }
    // epilogue
    #pragma unroll
    for (int j4 = 0; j4 < 4; ++j4) {
        int n = n0 + j4 * 16 + m_l;
        if (n < N) {
            #pragma unroll
            for (int reg = 0; reg < 4; ++reg) {
                int m = m0 + wave * 16 + q * 4 + reg;
                float* cp = C + (size_t)m * N + n;
                if (accumulate) *cp += acc[j4][reg];
                else            *cp  = acc[j4][reg];
            }
        }
    }
}

// ---- causal depthwise conv (k=4) + silu: xz[:,:, :512] -> xc (f32 + bf16) --
__global__ __launch_bounds__(256) void conv_silu_kernel(
    const float* __restrict__ xz, const float* __restrict__ cw,
    const float* __restrict__ cb, float* __restrict__ xc,
    unsigned short* __restrict__ xcb)
{
    int idx = blockIdx.x * 256 + threadIdx.x;   // B*L*DIN, d fastest
    int d = idx & (DIN - 1);
    int bl = idx >> 9;
    int l = bl & (L_ - 1);
    int b = bl >> 10;
    float acc = cb[d];
    #pragma unroll
    for (int k = 0; k < 4; ++k) {
        int ls = l - 3 + k;
        if (ls >= 0)
            acc = fmaf(xz[((size_t)(b * L_ + ls)) * (2 * DIN) + d], cw[d * 4 + k], acc);
    }
    float v = siluf(acc);
    xc[idx] = v;
    xcb[idx] = f2bf(v);
}

// ==== chunked selective scan, thread-per-channel, fused delta recompute ====
// thread = (b, chunk c, channel d); lane index = d (coalesced xc/y).
// delta = softplus(dbc[bl,0:16] . dt_w[d,:] + dt_b[d]) recomputed in both
// passes (dbc row is block-uniform scalar loads; dt_w[d] loaded once).

__global__ __launch_bounds__(256) void scan_summary_kernel(
    const float* __restrict__ dbc, const float* __restrict__ xc,
    const float* __restrict__ A_log, const float* __restrict__ dt_w,
    const float* __restrict__ dt_b,
    float* __restrict__ S, float* __restrict__ H)
{
    const int d = blockIdx.x * 256 + threadIdx.x;
    const int c = blockIdx.y;
    const int b = blockIdx.z;
    float A[NST], tw[DTR];
    #pragma unroll
    for (int j = 0; j < NST; ++j) A[j] = -__expf(A_log[d * NST + j]);
    #pragma unroll
    for (int r = 0; r < DTR; ++r) tw[r] = dt_w[d * DTR + r];
    const float tb = dt_b[d];
    const int l0 = c * CT;
    const float* xp = xc  + ((size_t)(b * L_ + l0)) * DIN + d;
    const float* bc = dbc + ((size_t)(b * L_ + l0)) * 48;
    float h[NST];
    #pragma unroll
    for (int j = 0; j < NST; ++j) h[j] = 0.f;
    float ssum = 0.f;
    #pragma unroll 4
    for (int t = 0; t < CT; ++t) {
        const float* br = bc + t * 48;        // block-uniform row
        float acc = tb;
        #pragma unroll
        for (int r = 0; r < DTR; ++r) acc = fmaf(br[r], tw[r], acc);
        float dlt = softplusf(acc);
        float xcv = xp[t * DIN];
        float t0 = dlt * xcv;
        ssum += dlt;
        #pragma unroll
        for (int j = 0; j < NST; ++j) {
            float dA = __expf(A[j] * dlt);
            h[j] = fmaf(dA, h[j], t0 * br[DTR + j]);
        }
    }
    S[((size_t)b * CHK + c) * DIN + d] = ssum;
    float* Hp = H + (((size_t)b * CHK + c) * DIN + d) * NST;
    #pragma unroll
    for (int j = 0; j < NST; j += 4)
        *(float4*)(Hp + j) = make_float4(h[j], h[j + 1], h[j + 2], h[j + 3]);
}

__global__ __launch_bounds__(256) void scan_prefix_kernel(
    const float* __restrict__ S, float* __restrict__ H,
    const float* __restrict__ A_log)
{
    int idx = blockIdx.x * 256 + threadIdx.x;  // B*DIN*NST, n fastest
    int n = idx & (NST - 1);
    int dn = idx >> 4;
    int d = dn & (DIN - 1);
    int b = dn >> 9;
    float A = -__expf(A_log[d * NST + n]);
    float hprev = 0.f;
    const float* Sp = S + (size_t)b * CHK * DIN + d;
    float* Hp = H + ((size_t)b * CHK * DIN + d) * NST + n;
    for (int c = 0; c < CHK; ++c) {
        float Hc = Hp[(size_t)c * DIN * NST];
        float Sc = Sp[(size_t)c * DIN];
        Hp[(size_t)c * DIN * NST] = hprev;                  // h_in(c)
        hprev = fmaf(__expf(A * Sc), hprev, Hc);
    }
}

__global__ __launch_bounds__(256) void scan_apply_kernel(
    const float* __restrict__ dbc, const float* __restrict__ xc,
    const float* __restrict__ xz, const float* __restrict__ A_log,
    const float* __restrict__ dt_w, const float* __restrict__ dt_b,
    const float* __restrict__ Dskip, const float* __restrict__ H,
    unsigned short* __restrict__ y)
{
    const int d = blockIdx.x * 256 + threadIdx.x;
    const int c = blockIdx.y;
    const int b = blockIdx.z;
    float A[NST], tw[DTR];
    #pragma unroll
    for (int j = 0; j < NST; ++j) A[j] = -__expf(A_log[d * NST + j]);
    #pragma unroll
    for (int r = 0; r < DTR; ++r) tw[r] = dt_w[d * DTR + r];
    const float tb = dt_b[d];
    const float Dsk = Dskip[d];
    const int l0 = c * CT;
    const float* xp = xc  + ((size_t)(b * L_ + l0)) * DIN + d;
    const float* bc = dbc + ((size_t)(b * L_ + l0)) * 48;
    const float* zp = xz  + ((size_t)(b * L_ + l0)) * (2 * DIN) + DIN + d;
    unsigned short* yp = y + ((size_t)(b * L_ + l0)) * DIN + d;

    const float* Hp = H + (((size_t)b * CHK + c) * DIN + d) * NST;
    float h[NST];
    #pragma unroll
    for (int j = 0; j < NST; j += 4) {
        float4 hv = *(const float4*)(Hp + j);
        h[j] = hv.x; h[j + 1] = hv.y; h[j + 2] = hv.z; h[j + 3] = hv.w;
    }

    #pragma unroll 4
    for (int t = 0; t < CT; ++t) {
        const float* br = bc + t * 48;        // block-uniform row
        float acc = tb;
        #pragma unroll
        for (int r = 0; r < DTR; ++r) acc = fmaf(br[r], tw[r], acc);
        float dlt = softplusf(acc);
        float xcv = xp[t * DIN];
        float zv  = zp[t * (2 * DIN)];
        float t0 = dlt * xcv;
        float p = 0.f;
        #pragma unroll
        for (int j = 0; j < NST; ++j) {
            float dA = __expf(A[j] * dlt);
            h[j] = fmaf(dA, h[j], t0 * br[DTR + j]);
            p = fmaf(h[j], br[DTR + NST + j], p);
        }
        yp[t * DIN] = f2bf((p + xcv * Dsk) * siluf(zv));
    }
}

// ---- mean over L -> layernorm -> classifier; one block per batch ----
__global__ __launch_bounds__(256) void head_kernel(
    const float* __restrict__ h, const float* __restrict__ fn_w,
    const float* __restrict__ fn_b, const float* __restrict__ cls_w,
    const float* __restrict__ cls_b, float* __restrict__ out)
{
    int b = blockIdx.x, t = threadIdx.x;
    const float* hp = h + (size_t)b * L_ * DM + t;
    float s = 0.f;
    for (int l = 0; l < L_; ++l) s += hp[(size_t)l * DM];
    s *= (1.f / L_);
    float a = s, q = s * s;
    block_reduce2(a, q);
    float mu = a * (1.f / DM);
    float var = q * (1.f / DM) - mu * mu;
    float v = (s - mu) * rsqrtf(var + 1e-5f) * fn_w[t] + fn_b[t];
    __shared__ float pooled[DM];
    pooled[t] = v;
    __syncthreads();
    if (t < 10) {
        float acc = cls_b[t];
        for (int d2 = 0; d2 < DM; ++d2)
            acc = fmaf(pooled[d2], cls_w[t * DM + d2], acc);
        out[b * 10 + t] = acc;
    }
}

extern "C" void kernel_launch(void* const* d_in, const int* in_sizes, int n_in,
                              void* d_out, int out_size, void* d_ws, size_t ws_size,
                              hipStream_t stream)
{
    const float* x    = (const float*)d_in[0];
    const float* ipw  = (const float*)d_in[1];
    const float* ipb  = (const float*)d_in[2];
    const float* inw  = (const float*)d_in[3];
    const float* cw   = (const float*)d_in[4];
    const float* cb   = (const float*)d_in[5];
    const float* xpw  = (const float*)d_in[6];
    const float* dtw  = (const float*)d_in[7];
    const float* dtb  = (const float*)d_in[8];
    const float* alog = (const float*)d_in[9];
    const float* dsk  = (const float*)d_in[10];
    const float* opw  = (const float*)d_in[11];
    const float* lnw  = (const float*)d_in[12];
    const float* lnb  = (const float*)d_in[13];
    const float* fnw  = (const float*)d_in[14];
    const float* fnb  = (const float*)d_in[15];
    const float* clw  = (const float*)d_in[16];
    const float* clb  = (const float*)d_in[17];

    // workspace layout (float units)
    float* ws     = (float*)d_ws;
    float* hbuf   = ws;                                   // B*L*DM = 1,048,576 f
    float* xzbuf  = hbuf   + (size_t)B_ * L_ * DM;        // 4,194,304 f
    float* xcbuf  = xzbuf  + (size_t)B_ * L_ * 2 * DIN;   // 2,097,152 f
    float* dbcbuf = xcbuf  + (size_t)B_ * L_ * DIN;       //   196,608 f
    float* Sbuf   = dbcbuf + (size_t)B_ * L_ * 48;        //    65,536 f
    float* Hbuf   = Sbuf   + (size_t)B_ * CHK * DIN;      // 1,048,576 f
    float* tail   = Hbuf   + (size_t)B_ * CHK * DIN * NST;
    unsigned short* lnb16 = (unsigned short*)tail;                  // B*L*DM sh
    unsigned short* xcb16 = lnb16 + (size_t)B_ * L_ * DM;           // B*L*DIN sh
    unsigned short* yb16  = xcb16 + (size_t)B_ * L_ * DIN;          // B*L*DIN sh
    unsigned short* w16   = yb16  + (size_t)B_ * L_ * DIN;          // weights
    unsigned short* inw16 = w16;                          // 4*1024*256
    unsigned short* xpw16 = inw16 + (size_t)4 * 1024 * DM;// 4*48*512
    unsigned short* opw16 = xpw16 + (size_t)4 * 48 * DIN; // 4*256*512

    const int BL = B_ * L_;                               // 4096
    const int NIN = 4 * 1024 * DM, NXP = 4 * 48 * DIN, NOP = 4 * DM * DIN;

    // one-time (per launch) weight conversions
    f2bf_kernel<<<(NIN + 255) / 256, 256, 0, stream>>>(inw, inw16, NIN);
    f2bf_kernel<<<(NXP + 255) / 256, 256, 0, stream>>>(xpw, xpw16, NXP);
    f2bf_kernel<<<(NOP + 255) / 256, 256, 0, stream>>>(opw, opw16, NOP);

    input_proj_kernel<<<BL * DM / 256, 256, 0, stream>>>(x, ipw, ipb, hbuf);

    for (int i = 0; i < 4; ++i) {
        ln_kernel<<<BL, 256, 0, stream>>>(hbuf, lnw + i * DM, lnb + i * DM, lnb16);
        // xz = ln @ in_w^T   [4096,1024] fp32 out
        gemm_bt_bf16<<<dim3(2 * DIN / 64, BL / 64), 256, 0, stream>>>(
            lnb16, inw16 + (size_t)i * 1024 * DM, xzbuf, BL, 2 * DIN, DM, DM, 0);
        conv_silu_kernel<<<BL * DIN / 256, 256, 0, stream>>>(
            xzbuf, cw + i * DIN * 4, cb + i * DIN, xcbuf, xcb16);
        // dbc = xc @ xp_w^T  [4096,48]
        gemm_bt_bf16<<<dim3(1, BL / 64), 256, 0, stream>>>(
            xcb16, xpw16 + (size_t)i * 48 * DIN, dbcbuf, BL, 48, DIN, DIN, 0);
        // chunked scan (delta fused): summary -> prefix -> apply
        scan_summary_kernel<<<dim3(DIN / 256, CHK, B_), 256, 0, stream>>>(
            dbcbuf, xcbuf, alog + i * DIN * NST, dtw + i * DIN * DTR,
            dtb + i * DIN, Sbuf, Hbuf);
        scan_prefix_kernel<<<B_ * DIN * NST / 256, 256, 0, stream>>>(
            Sbuf, Hbuf, alog + i * DIN * NST);
        scan_apply_kernel<<<dim3(DIN / 256, CHK, B_), 256, 0, stream>>>(
            dbcbuf, xcbuf, xzbuf, alog + i * DIN * NST, dtw + i * DIN * DTR,
            dtb + i * DIN, dsk + i * DIN, Hbuf, yb16);
        // h += y @ out_w^T   [4096,256]
        gemm_bt_bf16<<<dim3(DM / 64, BL / 64), 256, 0, stream>>>(
            yb16, opw16 + (size_t)i * DM * DIN, hbuf, BL, DM, DIN, DIN, 1);
    }

    head_kernel<<<B_, 256, 0, stream>>>(hbuf, fnw, fnb, clw, clb, (float*)d_out);
}